// Round 1
// baseline (2287.770 us; speedup 1.0000x reference)
//
#include <hip/hip_runtime.h>
#include <math.h>

#define T_LEN 2048
#define BSZ   4
#define EMB   768
#define NH    12
#define DH    64
#define NTOK  (T_LEN * BSZ)      // 8192
#define N_QKV (3 * EMB)          // 2304

// ---------------------------------------------------------------------------
// GEMM: C = A @ W^T (+ bias).  A: M x K row-major, W: N x K row-major.
// 128x128 tile, BK=16, 256 threads, 8x8 microtile.
// MODE 0: write C (M x N row-major) = out-projection
// MODE 1: scatter into q/k/v buffers laid out [B][H][T][DH], scale q by 0.125
// ---------------------------------------------------------------------------
template <int MODE>
__global__ __launch_bounds__(256) void gemm_xwt(
    const float* __restrict__ A, const float* __restrict__ W,
    const float* __restrict__ bias, float* __restrict__ C,
    float* __restrict__ qb, float* __restrict__ kb, float* __restrict__ vb,
    int M, int N, int K)
{
    __shared__ float As[16][132];
    __shared__ float Bs[16][132];

    const int tid = threadIdx.x;
    const int tx = tid & 15;        // 0..15 -> N direction
    const int ty = tid >> 4;        // 0..15 -> M direction
    const int lr = tid >> 1;        // 0..127: tile row to load
    const int lc = (tid & 1) << 3;  // 0 or 8: tile col (k) to load

    const float* ap = A + (size_t)(blockIdx.x * 128 + lr) * K + lc;
    const float* wp = W + (size_t)(blockIdx.y * 128 + lr) * K + lc;

    float acc[8][8];
#pragma unroll
    for (int i = 0; i < 8; ++i)
#pragma unroll
        for (int j = 0; j < 8; ++j) acc[i][j] = 0.f;

    for (int kt = 0; kt < K; kt += 16) {
        float4 a0 = *(const float4*)(ap + kt);
        float4 a1 = *(const float4*)(ap + kt + 4);
        float4 b0 = *(const float4*)(wp + kt);
        float4 b1 = *(const float4*)(wp + kt + 4);
        __syncthreads();
        As[lc + 0][lr] = a0.x; As[lc + 1][lr] = a0.y;
        As[lc + 2][lr] = a0.z; As[lc + 3][lr] = a0.w;
        As[lc + 4][lr] = a1.x; As[lc + 5][lr] = a1.y;
        As[lc + 6][lr] = a1.z; As[lc + 7][lr] = a1.w;
        Bs[lc + 0][lr] = b0.x; Bs[lc + 1][lr] = b0.y;
        Bs[lc + 2][lr] = b0.z; Bs[lc + 3][lr] = b0.w;
        Bs[lc + 4][lr] = b1.x; Bs[lc + 5][lr] = b1.y;
        Bs[lc + 6][lr] = b1.z; Bs[lc + 7][lr] = b1.w;
        __syncthreads();
#pragma unroll
        for (int k = 0; k < 16; ++k) {
            float a[8], b[8];
            *(float4*)&a[0] = *(const float4*)&As[k][ty * 8];
            *(float4*)&a[4] = *(const float4*)&As[k][ty * 8 + 4];
            *(float4*)&b[0] = *(const float4*)&Bs[k][tx * 8];
            *(float4*)&b[4] = *(const float4*)&Bs[k][tx * 8 + 4];
#pragma unroll
            for (int i = 0; i < 8; ++i)
#pragma unroll
                for (int j = 0; j < 8; ++j)
                    acc[i][j] = fmaf(a[i], b[j], acc[i][j]);
        }
    }

    const int row0 = blockIdx.x * 128 + ty * 8;
    const int col0 = blockIdx.y * 128 + tx * 8;
    float bsv[8];
#pragma unroll
    for (int j = 0; j < 8; ++j) bsv[j] = bias[col0 + j];

    if (MODE == 0) {
#pragma unroll
        for (int i = 0; i < 8; ++i) {
            float4 v0 = make_float4(acc[i][0] + bsv[0], acc[i][1] + bsv[1],
                                    acc[i][2] + bsv[2], acc[i][3] + bsv[3]);
            float4 v1 = make_float4(acc[i][4] + bsv[4], acc[i][5] + bsv[5],
                                    acc[i][6] + bsv[6], acc[i][7] + bsv[7]);
            float* dst = C + (size_t)(row0 + i) * N + col0;
            *(float4*)(dst)     = v0;
            *(float4*)(dst + 4) = v1;
        }
    } else {
        // col -> (section, head, d).  128-wide tiles never straddle a section
        // (768 % 128 == 0) and a thread's 8 cols never straddle a head (8|64).
        const int sec = col0 / EMB;
        const int e0  = col0 % EMB;
        const int h   = e0 >> 6;
        const int d0  = e0 & 63;
        float* base = (sec == 0) ? qb : (sec == 1) ? kb : vb;
        const float scale = (sec == 0) ? 0.125f : 1.0f;  // Dh^-0.5, q only
#pragma unroll
        for (int i = 0; i < 8; ++i) {
            const int n = row0 + i;
            const int t = n >> 2;      // n = t*B + b, B = 4
            const int b = n & 3;
            float* dst = base + ((size_t)((b * NH + h) * T_LEN + t)) * DH + d0;
            float4 v0 = make_float4((acc[i][0] + bsv[0]) * scale,
                                    (acc[i][1] + bsv[1]) * scale,
                                    (acc[i][2] + bsv[2]) * scale,
                                    (acc[i][3] + bsv[3]) * scale);
            float4 v1 = make_float4((acc[i][4] + bsv[4]) * scale,
                                    (acc[i][5] + bsv[5]) * scale,
                                    (acc[i][6] + bsv[6]) * scale,
                                    (acc[i][7] + bsv[7]) * scale);
            *(float4*)(dst)     = v0;
            *(float4*)(dst + 4) = v1;
        }
    }
}

// ---------------------------------------------------------------------------
// Flash attention, fp32. One thread owns one q row (q[64], o[64] in VGPRs).
// K/V rows are read with wave-uniform addresses -> scalar loads (SGPR
// broadcast), no LDS. Masked src rows skipped entirely (wave-uniform branch).
// Online softmax with rare-rescale branch.
// ---------------------------------------------------------------------------
__global__ __launch_bounds__(256) void attn_kernel(
    const float* __restrict__ qb, const float* __restrict__ kb,
    const float* __restrict__ vb, const float* __restrict__ attn_bias,
    const int* __restrict__ mask, float* __restrict__ ab)
{
    const int bh = blockIdx.y;           // b*NH + h
    const int b  = bh / NH;
    const int h  = bh % NH;
    const int tq = blockIdx.x * 256 + threadIdx.x;

    const size_t base = (size_t)bh * T_LEN * DH;
    const float* qp = qb + base + (size_t)tq * DH;

    float q[DH];
#pragma unroll
    for (int d4 = 0; d4 < 16; ++d4)
        *(float4*)&q[d4 * 4] = *(const float4*)(qp + d4 * 4);

    float o[DH];
#pragma unroll
    for (int d = 0; d < DH; ++d) o[d] = 0.f;
    float m = -INFINITY, l = 0.f;

    const float* kp = kb + base;
    const float* vp = vb + base;

    for (int s = 0; s < T_LEN; ++s) {
        if (mask[s * BSZ + b]) continue;          // wave-uniform skip
        const float* kr = kp + (size_t)s * DH;
        float sc = attn_bias[s * BSZ + b];
#pragma unroll
        for (int d4 = 0; d4 < 16; ++d4) {
            float4 kv = *(const float4*)(kr + 4 * d4);
            sc = fmaf(q[4 * d4 + 0], kv.x, sc);
            sc = fmaf(q[4 * d4 + 1], kv.y, sc);
            sc = fmaf(q[4 * d4 + 2], kv.z, sc);
            sc = fmaf(q[4 * d4 + 3], kv.w, sc);
        }
        const float* vr = vp + (size_t)s * DH;
        if (sc > m) {
            const float r = __expf(m - sc);       // m = -inf first time -> 0
            l = l * r + 1.f;
#pragma unroll
            for (int d4 = 0; d4 < 16; ++d4) {
                float4 vv = *(const float4*)(vr + 4 * d4);
                o[4 * d4 + 0] = fmaf(o[4 * d4 + 0], r, vv.x);
                o[4 * d4 + 1] = fmaf(o[4 * d4 + 1], r, vv.y);
                o[4 * d4 + 2] = fmaf(o[4 * d4 + 2], r, vv.z);
                o[4 * d4 + 3] = fmaf(o[4 * d4 + 3], r, vv.w);
            }
            m = sc;
        } else {
            const float p = __expf(sc - m);
            l += p;
#pragma unroll
            for (int d4 = 0; d4 < 16; ++d4) {
                float4 vv = *(const float4*)(vr + 4 * d4);
                o[4 * d4 + 0] = fmaf(p, vv.x, o[4 * d4 + 0]);
                o[4 * d4 + 1] = fmaf(p, vv.y, o[4 * d4 + 1]);
                o[4 * d4 + 2] = fmaf(p, vv.z, o[4 * d4 + 2]);
                o[4 * d4 + 3] = fmaf(p, vv.w, o[4 * d4 + 3]);
            }
        }
    }

    const float inv = 1.f / l;
    float* op = ab + ((size_t)tq * BSZ + b) * EMB + h * DH;
#pragma unroll
    for (int d4 = 0; d4 < 16; ++d4) {
        float4 v = make_float4(o[4 * d4 + 0] * inv, o[4 * d4 + 1] * inv,
                               o[4 * d4 + 2] * inv, o[4 * d4 + 3] * inv);
        *(float4*)(op + 4 * d4) = v;
    }
}

// ---------------------------------------------------------------------------
extern "C" void kernel_launch(void* const* d_in, const int* in_sizes, int n_in,
                              void* d_out, int out_size, void* d_ws, size_t ws_size,
                              hipStream_t stream)
{
    const float* x     = (const float*)d_in[0];
    const int*   mask  = (const int*)d_in[1];   // bool -> int32 per harness contract
    const float* abias = (const float*)d_in[2];
    const float* wqkv  = (const float*)d_in[3];
    const float* bqkv  = (const float*)d_in[4];
    const float* wout  = (const float*)d_in[5];
    const float* bout  = (const float*)d_in[6];
    float* out = (float*)d_out;

    const size_t per = (size_t)BSZ * NH * T_LEN * DH;  // 6,291,456 floats
    float* qb = (float*)d_ws;
    float* kb = qb + per;
    float* vb = kb + per;
    float* ab = vb + per;

    // QKV projection + scatter to (B,H,T,Dh) with q-scaling
    gemm_xwt<1><<<dim3(NTOK / 128, N_QKV / 128), 256, 0, stream>>>(
        x, wqkv, bqkv, nullptr, qb, kb, vb, NTOK, N_QKV, EMB);

    // flash attention -> (T,B,E)
    attn_kernel<<<dim3(T_LEN / 256, BSZ * NH), 256, 0, stream>>>(
        qb, kb, vb, abias, mask, ab);

    // out projection
    gemm_xwt<0><<<dim3(NTOK / 128, EMB / 128), 256, 0, stream>>>(
        ab, wout, bout, out, nullptr, nullptr, nullptr, NTOK, EMB, EMB);
}

// Round 2
// 1194.870 us; speedup vs baseline: 1.9147x; 1.9147x over previous
//
#include <hip/hip_runtime.h>
#include <math.h>

#define T_LEN 2048
#define BSZ   4
#define EMB   768
#define NH    12
#define DH    64
#define NTOK  (T_LEN * BSZ)      // 8192
#define N_QKV (3 * EMB)          // 2304
#define BH    (BSZ * NH)         // 48

// ---------------------------------------------------------------------------
// GEMM: C = A @ W^T (+ bias).  A: M x K row-major, W: N x K row-major.
// 128x128 tile, BK=16, 256 threads, 8x8 microtile.  (unchanged from R0)
// ---------------------------------------------------------------------------
template <int MODE>
__global__ __launch_bounds__(256) void gemm_xwt(
    const float* __restrict__ A, const float* __restrict__ W,
    const float* __restrict__ bias, float* __restrict__ C,
    float* __restrict__ qb, float* __restrict__ kb, float* __restrict__ vb,
    int M, int N, int K)
{
    __shared__ float As[16][132];
    __shared__ float Bs[16][132];

    const int tid = threadIdx.x;
    const int tx = tid & 15;
    const int ty = tid >> 4;
    const int lr = tid >> 1;
    const int lc = (tid & 1) << 3;

    const float* ap = A + (size_t)(blockIdx.x * 128 + lr) * K + lc;
    const float* wp = W + (size_t)(blockIdx.y * 128 + lr) * K + lc;

    float acc[8][8];
#pragma unroll
    for (int i = 0; i < 8; ++i)
#pragma unroll
        for (int j = 0; j < 8; ++j) acc[i][j] = 0.f;

    for (int kt = 0; kt < K; kt += 16) {
        float4 a0 = *(const float4*)(ap + kt);
        float4 a1 = *(const float4*)(ap + kt + 4);
        float4 b0 = *(const float4*)(wp + kt);
        float4 b1 = *(const float4*)(wp + kt + 4);
        __syncthreads();
        As[lc + 0][lr] = a0.x; As[lc + 1][lr] = a0.y;
        As[lc + 2][lr] = a0.z; As[lc + 3][lr] = a0.w;
        As[lc + 4][lr] = a1.x; As[lc + 5][lr] = a1.y;
        As[lc + 6][lr] = a1.z; As[lc + 7][lr] = a1.w;
        Bs[lc + 0][lr] = b0.x; Bs[lc + 1][lr] = b0.y;
        Bs[lc + 2][lr] = b0.z; Bs[lc + 3][lr] = b0.w;
        Bs[lc + 4][lr] = b1.x; Bs[lc + 5][lr] = b1.y;
        Bs[lc + 6][lr] = b1.z; Bs[lc + 7][lr] = b1.w;
        __syncthreads();
#pragma unroll
        for (int k = 0; k < 16; ++k) {
            float a[8], b[8];
            *(float4*)&a[0] = *(const float4*)&As[k][ty * 8];
            *(float4*)&a[4] = *(const float4*)&As[k][ty * 8 + 4];
            *(float4*)&b[0] = *(const float4*)&Bs[k][tx * 8];
            *(float4*)&b[4] = *(const float4*)&Bs[k][tx * 8 + 4];
#pragma unroll
            for (int i = 0; i < 8; ++i)
#pragma unroll
                for (int j = 0; j < 8; ++j)
                    acc[i][j] = fmaf(a[i], b[j], acc[i][j]);
        }
    }

    const int row0 = blockIdx.x * 128 + ty * 8;
    const int col0 = blockIdx.y * 128 + tx * 8;
    float bsv[8];
#pragma unroll
    for (int j = 0; j < 8; ++j) bsv[j] = bias[col0 + j];

    if (MODE == 0) {
#pragma unroll
        for (int i = 0; i < 8; ++i) {
            float4 v0 = make_float4(acc[i][0] + bsv[0], acc[i][1] + bsv[1],
                                    acc[i][2] + bsv[2], acc[i][3] + bsv[3]);
            float4 v1 = make_float4(acc[i][4] + bsv[4], acc[i][5] + bsv[5],
                                    acc[i][6] + bsv[6], acc[i][7] + bsv[7]);
            float* dst = C + (size_t)(row0 + i) * N + col0;
            *(float4*)(dst)     = v0;
            *(float4*)(dst + 4) = v1;
        }
    } else {
        const int sec = col0 / EMB;
        const int e0  = col0 % EMB;
        const int h   = e0 >> 6;
        const int d0  = e0 & 63;
        float* base = (sec == 0) ? qb : (sec == 1) ? kb : vb;
        const float scale = (sec == 0) ? 0.125f : 1.0f;
#pragma unroll
        for (int i = 0; i < 8; ++i) {
            const int n = row0 + i;
            const int t = n >> 2;
            const int b = n & 3;
            float* dst = base + ((size_t)((b * NH + h) * T_LEN + t)) * DH + d0;
            float4 v0 = make_float4((acc[i][0] + bsv[0]) * scale,
                                    (acc[i][1] + bsv[1]) * scale,
                                    (acc[i][2] + bsv[2]) * scale,
                                    (acc[i][3] + bsv[3]) * scale);
            float4 v1 = make_float4((acc[i][4] + bsv[4]) * scale,
                                    (acc[i][5] + bsv[5]) * scale,
                                    (acc[i][6] + bsv[6]) * scale,
                                    (acc[i][7] + bsv[7]) * scale);
            *(float4*)(dst)     = v0;
            *(float4*)(dst + 4) = v1;
        }
    }
}

// ---------------------------------------------------------------------------
// Mask compaction: per batch b, list of unmasked src indices + gathered bias,
// padded to a multiple of 16 with (idx=0, bias=-1e30) sentinels.
// One wave per b.
// ---------------------------------------------------------------------------
__global__ __launch_bounds__(64) void compact_mask(
    const int* __restrict__ mask, const float* __restrict__ abias,
    int* __restrict__ cidx, float* __restrict__ cbias, int* __restrict__ ccount)
{
    const int b = blockIdx.x;
    const int lane = threadIdx.x;
    int* ip = cidx + b * T_LEN;
    float* bp = cbias + b * T_LEN;

    int base = 0;
    for (int c = 0; c < T_LEN / 64; ++c) {
        const int s = c * 64 + lane;
        const int mv = mask[s * BSZ + b];
        const float bv = abias[s * BSZ + b];
        const unsigned long long bal = __ballot(mv == 0);
        const int pos = __popcll(bal & ((1ull << lane) - 1ull));
        if (mv == 0) { ip[base + pos] = s; bp[base + pos] = bv; }
        base += __popcll(bal);
    }
    const int npad = (base + 15) & ~15;
    if (lane < npad - base) { ip[base + lane] = 0; bp[base + lane] = -1e30f; }
    if (lane == 0) ccount[b] = npad;
}

// ---------------------------------------------------------------------------
// Flash attention, fp32, tile-of-8 src rows. One thread = one q row.
// K/V reads are wave-uniform (compacted gather) -> scalar loads (SGPR),
// zero LDS. SPLITTED=1: grid.z splits src range, writes unnormalized o + (m,l).
// SPLITTED=0: direct normalized write to ab in (T,B,E) layout.
// ---------------------------------------------------------------------------
template <int SPLITTED>
__global__ __launch_bounds__(256) void attn2(
    const float* __restrict__ qb, const float* __restrict__ kb,
    const float* __restrict__ vb, const int* __restrict__ cidx,
    const float* __restrict__ cbias, const int* __restrict__ ccount,
    float* __restrict__ opart, float* __restrict__ ml, float* __restrict__ ab)
{
    const int bh = blockIdx.y;
    const int b  = bh / NH;
    const int h  = bh % NH;
    const int tq = blockIdx.x * 256 + threadIdx.x;

    const size_t base = (size_t)bh * T_LEN * DH;
    const float* qp = qb + base + (size_t)tq * DH;
    const float* kp = kb + base;
    const float* vp = vb + base;

    float4 q4[16];
#pragma unroll
    for (int d4 = 0; d4 < 16; ++d4)
        q4[d4] = *(const float4*)(qp + d4 * 4);

    float4 o4[16];
#pragma unroll
    for (int d4 = 0; d4 < 16; ++d4) o4[d4] = make_float4(0.f, 0.f, 0.f, 0.f);
    float m = -1e30f, l = 0.f;

    const int npad = ccount[b];
    int i0, i1;
    if (SPLITTED) {
        const int chunk = npad >> 1;          // npad multiple of 16 -> chunk of 8
        i0 = blockIdx.z * chunk;
        i1 = i0 + chunk;
    } else {
        i0 = 0; i1 = npad;
    }
    const int* idxp = cidx + b * T_LEN;
    const float* biasp = cbias + b * T_LEN;

    for (int i = i0; i < i1; i += 8) {
        int sj[8];
        float sc[8];
#pragma unroll
        for (int j = 0; j < 8; ++j) { sj[j] = idxp[i + j]; sc[j] = biasp[i + j]; }

        // --- QK: 8 independent dot chains, d-major ---
#pragma unroll
        for (int d4 = 0; d4 < 16; ++d4) {
            const float4 qv = q4[d4];
#pragma unroll
            for (int j = 0; j < 8; ++j) {
                const float4 kv = *(const float4*)(kp + (size_t)sj[j] * DH + d4 * 4);
                sc[j] = fmaf(qv.x, kv.x, sc[j]);
                sc[j] = fmaf(qv.y, kv.y, sc[j]);
                sc[j] = fmaf(qv.z, kv.z, sc[j]);
                sc[j] = fmaf(qv.w, kv.w, sc[j]);
            }
        }

        // --- online softmax update ---
        const float tm = fmaxf(fmaxf(fmaxf(sc[0], sc[1]), fmaxf(sc[2], sc[3])),
                               fmaxf(fmaxf(sc[4], sc[5]), fmaxf(sc[6], sc[7])));
        const float newm = fmaxf(m, tm);
        const float r = __expf(m - newm);
        m = newm;
        float p[8];
#pragma unroll
        for (int j = 0; j < 8; ++j) p[j] = __expf(sc[j] - newm);
        const float ps = ((p[0] + p[1]) + (p[2] + p[3])) + ((p[4] + p[5]) + (p[6] + p[7]));
        l = fmaf(l, r, ps);

        // --- rescale + PV ---
#pragma unroll
        for (int d4 = 0; d4 < 16; ++d4) {
            float4 ov = o4[d4];
            ov.x *= r; ov.y *= r; ov.z *= r; ov.w *= r;
#pragma unroll
            for (int j = 0; j < 8; ++j) {
                const float4 vv = *(const float4*)(vp + (size_t)sj[j] * DH + d4 * 4);
                ov.x = fmaf(p[j], vv.x, ov.x);
                ov.y = fmaf(p[j], vv.y, ov.y);
                ov.z = fmaf(p[j], vv.z, ov.z);
                ov.w = fmaf(p[j], vv.w, ov.w);
            }
            o4[d4] = ov;
        }
    }

    if (SPLITTED) {
        const int split = blockIdx.z;
        float* op = opart + ((size_t)(split * BH + bh) * T_LEN + tq) * DH;
#pragma unroll
        for (int d4 = 0; d4 < 16; ++d4) *(float4*)(op + d4 * 4) = o4[d4];
        float* mp = ml + ((size_t)(split * BH + bh) * T_LEN + tq) * 2;
        mp[0] = m; mp[1] = l;
    } else {
        const float inv = 1.f / l;
        float* op = ab + ((size_t)tq * BSZ + b) * EMB + h * DH;
#pragma unroll
        for (int d4 = 0; d4 < 16; ++d4) {
            float4 v = make_float4(o4[d4].x * inv, o4[d4].y * inv,
                                   o4[d4].z * inv, o4[d4].w * inv);
            *(float4*)(op + d4 * 4) = v;
        }
    }
}

// ---------------------------------------------------------------------------
// Combine the 2 split partials -> ab in (T,B,E) layout.
// ---------------------------------------------------------------------------
__global__ __launch_bounds__(256) void combine_kernel(
    const float* __restrict__ opart, const float* __restrict__ ml,
    float* __restrict__ ab)
{
    const int row = blockIdx.x * 256 + threadIdx.x;  // 0 .. BH*T_LEN-1
    const int bh = row >> 11;
    const int t  = row & 2047;
    const int b = bh / NH, h = bh % NH;

    const float* m0p = ml + ((size_t)(0 * BH + bh) * T_LEN + t) * 2;
    const float* m1p = ml + ((size_t)(1 * BH + bh) * T_LEN + t) * 2;
    const float m0 = m0p[0], l0 = m0p[1];
    const float m1 = m1p[0], l1 = m1p[1];
    const float M = fmaxf(m0, m1);
    const float w0 = __expf(m0 - M);
    const float w1 = __expf(m1 - M);
    const float inv = 1.f / (l0 * w0 + l1 * w1);

    const float* o0 = opart + ((size_t)(0 * BH + bh) * T_LEN + t) * DH;
    const float* o1 = opart + ((size_t)(1 * BH + bh) * T_LEN + t) * DH;
    float* op = ab + ((size_t)t * BSZ + b) * EMB + h * DH;
#pragma unroll
    for (int d4 = 0; d4 < 16; ++d4) {
        const float4 a = *(const float4*)(o0 + d4 * 4);
        const float4 c = *(const float4*)(o1 + d4 * 4);
        float4 v;
        v.x = (a.x * w0 + c.x * w1) * inv;
        v.y = (a.y * w0 + c.y * w1) * inv;
        v.z = (a.z * w0 + c.z * w1) * inv;
        v.w = (a.w * w0 + c.w * w1) * inv;
        *(float4*)(op + d4 * 4) = v;
    }
}

// ---------------------------------------------------------------------------
extern "C" void kernel_launch(void* const* d_in, const int* in_sizes, int n_in,
                              void* d_out, int out_size, void* d_ws, size_t ws_size,
                              hipStream_t stream)
{
    const float* x     = (const float*)d_in[0];
    const int*   mask  = (const int*)d_in[1];
    const float* abias = (const float*)d_in[2];
    const float* wqkv  = (const float*)d_in[3];
    const float* bqkv  = (const float*)d_in[4];
    const float* wout  = (const float*)d_in[5];
    const float* bout  = (const float*)d_in[6];
    float* out = (float*)d_out;

    const size_t per = (size_t)BH * T_LEN * DH;   // 6,291,456 floats

    // layout: cidx | cbias | ccount | qb kb vb ab | [opart(2) ml(2)]
    int*   cidx   = (int*)d_ws;
    float* cbias  = (float*)(cidx + BSZ * T_LEN);
    int*   ccount = (int*)(cbias + BSZ * T_LEN);
    float* qb = (float*)(ccount + 64);            // keep alignment
    float* kb = qb + per;
    float* vb = kb + per;
    float* ab = vb + per;
    float* opart = ab + per;
    float* mlbuf = opart + 2 * per;

    const size_t need_split =
        ((char*)(mlbuf + 2 * (size_t)BH * T_LEN * 2) - (char*)d_ws);
    const bool use_split = ws_size >= need_split;

    gemm_xwt<1><<<dim3(NTOK / 128, N_QKV / 128), 256, 0, stream>>>(
        x, wqkv, bqkv, nullptr, qb, kb, vb, NTOK, N_QKV, EMB);

    compact_mask<<<BSZ, 64, 0, stream>>>(mask, abias, cidx, cbias, ccount);

    if (use_split) {
        attn2<1><<<dim3(T_LEN / 256, BH, 2), 256, 0, stream>>>(
            qb, kb, vb, cidx, cbias, ccount, opart, mlbuf, nullptr);
        combine_kernel<<<(BH * T_LEN) / 256, 256, 0, stream>>>(opart, mlbuf, ab);
    } else {
        attn2<0><<<dim3(T_LEN / 256, BH, 1), 256, 0, stream>>>(
            qb, kb, vb, cidx, cbias, ccount, nullptr, nullptr, ab);
    }

    gemm_xwt<0><<<dim3(NTOK / 128, EMB / 128), 256, 0, stream>>>(
        ab, wout, bout, out, nullptr, nullptr, nullptr, NTOK, EMB, EMB);
}

// Round 3
// 314.832 us; speedup vs baseline: 7.2666x; 3.7953x over previous
//
#include <hip/hip_runtime.h>
#include <math.h>

#define T_LEN 2048
#define BSZ   4
#define EMB   768
#define NH    12
#define DH    64
#define NTOK  (T_LEN * BSZ)      // 8192
#define N_QKV (3 * EMB)          // 2304
#define BH    (BSZ * NH)         // 48

typedef _Float16 f16;
typedef _Float16 f16x8 __attribute__((ext_vector_type(8)));
typedef float    f32x4 __attribute__((ext_vector_type(4)));

#define MFMA16(a, b, c) __builtin_amdgcn_mfma_f32_16x16x32_f16(a, b, c, 0, 0, 0)

// ---------------------------------------------------------------------------
// Fused fp32 -> fp16 conversion of x, wqkv, wout into contiguous ws region.
// ---------------------------------------------------------------------------
__global__ __launch_bounds__(256) void conv3(
    const float* __restrict__ s0, const float* __restrict__ s1,
    const float* __restrict__ s2, int n0, int n1, int n2,
    f16* __restrict__ dst)
{
    const int gid = blockIdx.x * 256 + threadIdx.x;
    const int i = gid * 4;
    const int t01 = n0 + n1;
    const float* s;
    int off;
    if (i < n0)            { s = s0; off = i; }
    else if (i < t01)      { s = s1; off = i - n0; }
    else if (i < t01 + n2) { s = s2; off = i - t01; }
    else return;
    const float4 v = *(const float4*)(s + off);
    f16 hv[4] = {(f16)v.x, (f16)v.y, (f16)v.z, (f16)v.w};
    *(double*)(dst + i) = *(double*)hv;
}

// ---------------------------------------------------------------------------
// Mask compaction: per batch b, unmasked src indices + gathered bias,
// padded to a multiple of 32 with (idx=0, bias=-1e30) sentinels.
// ---------------------------------------------------------------------------
__global__ __launch_bounds__(64) void compact_mask(
    const int* __restrict__ mask, const float* __restrict__ abias,
    int* __restrict__ cidx, float* __restrict__ cbias, int* __restrict__ ccount)
{
    const int b = blockIdx.x;
    const int lane = threadIdx.x;
    int* ip = cidx + b * T_LEN;
    float* bp = cbias + b * T_LEN;

    int base = 0;
    for (int c = 0; c < T_LEN / 64; ++c) {
        const int s = c * 64 + lane;
        const int mv = mask[s * BSZ + b];
        const float bv = abias[s * BSZ + b];
        const unsigned long long bal = __ballot(mv == 0);
        const int pos = __popcll(bal & ((1ull << lane) - 1ull));
        if (mv == 0) { ip[base + pos] = s; bp[base + pos] = bv; }
        base += __popcll(bal);
    }
    const int npad = (base + 31) & ~31;
    if (lane < npad - base) { ip[base + lane] = 0; bp[base + lane] = -1e30f; }
    if (lane == 0) ccount[b] = npad;
}

// ---------------------------------------------------------------------------
// fp16 MFMA GEMM: C = A @ W^T (+bias).  A: MxK fp16 row-major, W: NxK fp16.
// 128x128 tile, BK=32, 4 waves, 64x64 per wave (4x4 frags of 16x16x32).
// MODE 0: C fp32 MxN.  MODE 1: scatter q/k/v fp16 [bh][t][dh], q scaled.
// ---------------------------------------------------------------------------
template <int MODE>
__global__ __launch_bounds__(256) void gemm_h(
    const f16* __restrict__ A, const f16* __restrict__ W,
    const float* __restrict__ bias, float* __restrict__ C,
    f16* __restrict__ qb, f16* __restrict__ kb, f16* __restrict__ vb,
    int M, int N, int K)
{
    __shared__ __align__(16) f16 As[128][40];   // 32 k + 8 pad
    __shared__ __align__(16) f16 Bs[128][40];

    const int tid = threadIdx.x;
    const int w = tid >> 6, l = tid & 63;
    const int wr = w >> 1, wc = w & 1;
    const int lg = l >> 4, lr = l & 15;

    const int bm = blockIdx.x * 128, bn = blockIdx.y * 128;

    // staging: chunk c in 0..511: row=c>>2, q=c&3 (8 fp16 = 16B each)
    const int r0 = tid >> 2, q0 = tid & 3;
    const f16* Ap = A + (size_t)(bm + r0) * K + q0 * 8;
    const f16* Wp = W + (size_t)(bn + r0) * K + q0 * 8;
    const size_t rstep = (size_t)64 * K;

    f32x4 acc[4][4];
#pragma unroll
    for (int i = 0; i < 4; ++i)
#pragma unroll
        for (int j = 0; j < 4; ++j) acc[i][j] = (f32x4)(0.f);

    int4 ra0 = *(const int4*)(Ap);
    int4 ra1 = *(const int4*)(Ap + rstep);
    int4 rb0 = *(const int4*)(Wp);
    int4 rb1 = *(const int4*)(Wp + rstep);

    for (int kt = 0; kt < K; kt += 32) {
        __syncthreads();
        *(int4*)&As[r0][q0 * 8]      = ra0;
        *(int4*)&As[64 + r0][q0 * 8] = ra1;
        *(int4*)&Bs[r0][q0 * 8]      = rb0;
        *(int4*)&Bs[64 + r0][q0 * 8] = rb1;
        __syncthreads();
        if (kt + 32 < K) {
            ra0 = *(const int4*)(Ap + kt + 32);
            ra1 = *(const int4*)(Ap + rstep + kt + 32);
            rb0 = *(const int4*)(Wp + kt + 32);
            rb1 = *(const int4*)(Wp + rstep + kt + 32);
        }
        f16x8 af[4], bf[4];
#pragma unroll
        for (int am = 0; am < 4; ++am)
            af[am] = *(const f16x8*)&As[wr * 64 + am * 16 + lr][lg * 8];
#pragma unroll
        for (int bnf = 0; bnf < 4; ++bnf)
            bf[bnf] = *(const f16x8*)&Bs[wc * 64 + bnf * 16 + lr][lg * 8];
#pragma unroll
        for (int am = 0; am < 4; ++am)
#pragma unroll
            for (int bnf = 0; bnf < 4; ++bnf)
                acc[am][bnf] = MFMA16(af[am], bf[bnf], acc[am][bnf]);
    }

    const int colb = bn + wc * 64;
    const int rowb = bm + wr * 64;
    float bv[4];
#pragma unroll
    for (int j = 0; j < 4; ++j) bv[j] = bias[colb + j * 16 + lr];

    if (MODE == 0) {
#pragma unroll
        for (int am = 0; am < 4; ++am)
#pragma unroll
            for (int bnf = 0; bnf < 4; ++bnf)
#pragma unroll
                for (int rg = 0; rg < 4; ++rg) {
                    const int row = rowb + am * 16 + lg * 4 + rg;
                    const int col = colb + bnf * 16 + lr;
                    C[(size_t)row * N + col] = acc[am][bnf][rg] + bv[bnf];
                }
    } else {
        const int sec = bn / EMB;   // 128-col blocks never straddle a section
        f16* basep = (sec == 0) ? qb : (sec == 1) ? kb : vb;
        const float scale = (sec == 0) ? 0.125f : 1.0f;
#pragma unroll
        for (int bnf = 0; bnf < 4; ++bnf) {
            const int col = colb + bnf * 16 + lr;
            const int e = col - sec * EMB;
            const int h = e >> 6, d = e & 63;
#pragma unroll
            for (int am = 0; am < 4; ++am)
#pragma unroll
                for (int rg = 0; rg < 4; ++rg) {
                    const int row = rowb + am * 16 + lg * 4 + rg;
                    const int t = row >> 2, b = row & 3;
                    basep[((size_t)((b * NH + h) * T_LEN + t)) * DH + d] =
                        (f16)((acc[am][bnf][rg] + bv[bnf]) * scale);
                }
        }
    }
}

// ---------------------------------------------------------------------------
// MFMA flash attention. Block: 1 head x 128 q-rows, 4 waves x 32 rows.
// KVBLK=32 over compacted src. Q frags in regs; K [src][64] LDS pad-72;
// V^T [dh][src] LDS pad-40; P via per-wave LDS pad-40.
// ---------------------------------------------------------------------------
__global__ __launch_bounds__(256) void attn_mfma(
    const f16* __restrict__ qh, const f16* __restrict__ kh,
    const f16* __restrict__ vh, const int* __restrict__ cidx,
    const float* __restrict__ cbias, const int* __restrict__ ccount,
    f16* __restrict__ abh)
{
    __shared__ __align__(16) f16 Kt[32][72];     // [src][dh 64 + 8 pad]
    __shared__ __align__(16) f16 Vt[64][40];     // [dh][src 32 + 8 pad]
    __shared__ __align__(16) f16 Pl[4][32][40];  // per-wave P
    __shared__ float bias_l[32];

    const int bh = blockIdx.y, b = bh / NH, h = bh % NH;
    const int tid = threadIdx.x, w = tid >> 6, l = tid & 63;
    const int lg = l >> 4, lr = l & 15;
    const size_t base = (size_t)bh * T_LEN * DH;
    const int q0 = blockIdx.x * 128 + w * 32;

    // Q fragments straight from global (row-major [t][dh], contiguous 16B)
    f16x8 qf[2][2];
#pragma unroll
    for (int mi = 0; mi < 2; ++mi)
#pragma unroll
        for (int ki = 0; ki < 2; ++ki)
            qf[mi][ki] = *(const f16x8*)(qh + base +
                (size_t)(q0 + mi * 16 + lr) * DH + ki * 32 + lg * 8);

    f32x4 o[2][4];
#pragma unroll
    for (int mi = 0; mi < 2; ++mi)
#pragma unroll
        for (int bn = 0; bn < 4; ++bn) o[mi][bn] = (f32x4)(0.f);
    float mrow[2][4], lrow[2][4];
#pragma unroll
    for (int mi = 0; mi < 2; ++mi)
#pragma unroll
        for (int rg = 0; rg < 4; ++rg) { mrow[mi][rg] = -1e30f; lrow[mi][rg] = 0.f; }

    const int npad = ccount[b];
    const int* idxp = cidx + b * T_LEN;
    const float* biasp = cbias + b * T_LEN;

    const int sr = tid >> 3, sc = tid & 7;     // K staging: row, 16B chunk
    const int vs = tid & 31, vc = tid >> 5;    // V staging: src, 16B chunk

    for (int i0 = 0; i0 < npad; i0 += 32) {
        const int ksrc = idxp[i0 + sr];
        const int4 kreg = *(const int4*)(kh + base + (size_t)ksrc * DH + sc * 8);
        const int vsrc = idxp[i0 + vs];
        const int4 vreg = *(const int4*)(vh + base + (size_t)vsrc * DH + vc * 8);
        const float bval = (tid < 32) ? biasp[i0 + tid] : 0.f;
        __syncthreads();                         // prev-iter LDS reads done
        *(int4*)&Kt[sr][sc * 8] = kreg;
        {
            f16 vv[8]; *(int4*)vv = vreg;
#pragma unroll
            for (int j = 0; j < 8; ++j) Vt[vc * 8 + j][vs] = vv[j];
        }
        if (tid < 32) bias_l[tid] = bval;
        __syncthreads();

        // --- S = Q K^T ---
        f32x4 s[2][2];
#pragma unroll
        for (int mi = 0; mi < 2; ++mi)
#pragma unroll
            for (int ni = 0; ni < 2; ++ni) s[mi][ni] = (f32x4)(0.f);
#pragma unroll
        for (int ni = 0; ni < 2; ++ni)
#pragma unroll
            for (int ki = 0; ki < 2; ++ki) {
                const f16x8 kf = *(const f16x8*)&Kt[ni * 16 + lr][ki * 32 + lg * 8];
#pragma unroll
                for (int mi = 0; mi < 2; ++mi)
                    s[mi][ni] = MFMA16(qf[mi][ki], kf, s[mi][ni]);
            }

        // --- bias + online softmax (rows = (lg*4+rg), cols = lane lr) ---
        float bcol[2];
#pragma unroll
        for (int ni = 0; ni < 2; ++ni) bcol[ni] = bias_l[ni * 16 + lr];

        float r_[2][4], p[2][2][4];
#pragma unroll
        for (int mi = 0; mi < 2; ++mi)
#pragma unroll
            for (int rg = 0; rg < 4; ++rg) {
                float s0 = s[mi][0][rg] + bcol[0];
                float s1 = s[mi][1][rg] + bcol[1];
                float mx = fmaxf(s0, s1);
                mx = fmaxf(mx, __shfl_xor(mx, 1));
                mx = fmaxf(mx, __shfl_xor(mx, 2));
                mx = fmaxf(mx, __shfl_xor(mx, 4));
                mx = fmaxf(mx, __shfl_xor(mx, 8));
                const float newm = fmaxf(mrow[mi][rg], mx);
                r_[mi][rg] = __expf(mrow[mi][rg] - newm);
                mrow[mi][rg] = newm;
                const float p0 = __expf(s0 - newm);
                const float p1 = __expf(s1 - newm);
                p[mi][0][rg] = p0; p[mi][1][rg] = p1;
                float ps = p0 + p1;
                ps += __shfl_xor(ps, 1);
                ps += __shfl_xor(ps, 2);
                ps += __shfl_xor(ps, 4);
                ps += __shfl_xor(ps, 8);
                lrow[mi][rg] = lrow[mi][rg] * r_[mi][rg] + ps;
            }

        // --- P -> LDS (C-layout -> A-frag layout) ---
#pragma unroll
        for (int mi = 0; mi < 2; ++mi)
#pragma unroll
            for (int ni = 0; ni < 2; ++ni)
#pragma unroll
                for (int rg = 0; rg < 4; ++rg)
                    Pl[w][mi * 16 + lg * 4 + rg][ni * 16 + lr] = (f16)p[mi][ni][rg];
        __syncthreads();

        // --- rescale O, then O += P V ---
#pragma unroll
        for (int mi = 0; mi < 2; ++mi)
#pragma unroll
            for (int bn = 0; bn < 4; ++bn)
#pragma unroll
                for (int rg = 0; rg < 4; ++rg) o[mi][bn][rg] *= r_[mi][rg];

        f16x8 pf[2];
#pragma unroll
        for (int mi = 0; mi < 2; ++mi)
            pf[mi] = *(const f16x8*)&Pl[w][mi * 16 + lr][lg * 8];
#pragma unroll
        for (int bn = 0; bn < 4; ++bn) {
            const f16x8 vf = *(const f16x8*)&Vt[bn * 16 + lr][lg * 8];
#pragma unroll
            for (int mi = 0; mi < 2; ++mi)
                o[mi][bn] = MFMA16(pf[mi], vf, o[mi][bn]);
        }
    }

    // --- epilogue: normalize, write abh [tok][EMB] fp16 ---
#pragma unroll
    for (int mi = 0; mi < 2; ++mi)
#pragma unroll
        for (int rg = 0; rg < 4; ++rg) {
            const float inv = 1.f / lrow[mi][rg];
            const int q = q0 + mi * 16 + lg * 4 + rg;
#pragma unroll
            for (int bn = 0; bn < 4; ++bn) {
                const int col = h * DH + bn * 16 + lr;
                abh[(size_t)(q * BSZ + b) * EMB + col] = (f16)(o[mi][bn][rg] * inv);
            }
        }
}

// ---------------------------------------------------------------------------
extern "C" void kernel_launch(void* const* d_in, const int* in_sizes, int n_in,
                              void* d_out, int out_size, void* d_ws, size_t ws_size,
                              hipStream_t stream)
{
    const float* x     = (const float*)d_in[0];
    const int*   mask  = (const int*)d_in[1];
    const float* abias = (const float*)d_in[2];
    const float* wqkv  = (const float*)d_in[3];
    const float* bqkv  = (const float*)d_in[4];
    const float* wout  = (const float*)d_in[5];
    const float* bout  = (const float*)d_in[6];
    float* out = (float*)d_out;

    const int n_x  = NTOK * EMB;      // 6291456
    const int n_wq = N_QKV * EMB;     // 1769472
    const int n_wo = EMB * EMB;       // 589824
    const size_t per = (size_t)BH * T_LEN * DH;  // 6291456

    f16* xh    = (f16*)d_ws;
    f16* wqkvh = xh + n_x;
    f16* wouth = wqkvh + n_wq;
    f16* qhb   = wouth + n_wo;
    f16* khb   = qhb + per;
    f16* vhb   = khb + per;
    f16* abh   = vhb + per;
    float* cbias = (float*)(abh + per);
    int*   cidx  = (int*)(cbias + BSZ * T_LEN);
    int*   ccnt  = cidx + BSZ * T_LEN;

    const int tot4 = (n_x + n_wq + n_wo) / 4;
    conv3<<<(tot4 + 255) / 256, 256, 0, stream>>>(
        x, wqkv, wout, n_x, n_wq, n_wo, xh);

    compact_mask<<<BSZ, 64, 0, stream>>>(mask, abias, cidx, cbias, ccnt);

    gemm_h<1><<<dim3(NTOK / 128, N_QKV / 128), 256, 0, stream>>>(
        xh, wqkvh, bqkv, nullptr, qhb, khb, vhb, NTOK, N_QKV, EMB);

    attn_mfma<<<dim3(T_LEN / 128, BH), 256, 0, stream>>>(
        qhb, khb, vhb, cidx, cbias, ccnt, abh);

    gemm_h<0><<<dim3(NTOK / 128, EMB / 128), 256, 0, stream>>>(
        abh, wouth, bout, out, nullptr, nullptr, nullptr, NTOK, EMB, EMB);
}

// Round 4
// 302.278 us; speedup vs baseline: 7.5684x; 1.0415x over previous
//
#include <hip/hip_runtime.h>
#include <math.h>

#define T_LEN 2048
#define BSZ   4
#define EMB   768
#define NH    12
#define DH    64
#define NTOK  (T_LEN * BSZ)      // 8192
#define N_QKV (3 * EMB)          // 2304
#define BH    (BSZ * NH)         // 48

typedef _Float16 f16;
typedef _Float16 f16x8 __attribute__((ext_vector_type(8)));
typedef float    f32x4 __attribute__((ext_vector_type(4)));

#define MFMA16(a, b, c) __builtin_amdgcn_mfma_f32_16x16x32_f16(a, b, c, 0, 0, 0)

// async global->LDS, 16B per lane; LDS dest = wave-uniform base + lane*16
__device__ __forceinline__ void gload16(const void* g, void* l) {
    __builtin_amdgcn_global_load_lds(
        (const __attribute__((address_space(1))) void*)g,
        (__attribute__((address_space(3))) void*)l, 16, 0, 0);
}

// ---------------------------------------------------------------------------
// fp32 -> fp16 conversion of x, wqkv, wout.
// ---------------------------------------------------------------------------
__global__ __launch_bounds__(256) void conv3(
    const float* __restrict__ s0, const float* __restrict__ s1,
    const float* __restrict__ s2, int n0, int n1, int n2,
    f16* __restrict__ dst)
{
    const int gid = blockIdx.x * 256 + threadIdx.x;
    const int i = gid * 4;
    const int t01 = n0 + n1;
    const float* s;
    int off;
    if (i < n0)            { s = s0; off = i; }
    else if (i < t01)      { s = s1; off = i - n0; }
    else if (i < t01 + n2) { s = s2; off = i - t01; }
    else return;
    const float4 v = *(const float4*)(s + off);
    f16 hv[4] = {(f16)v.x, (f16)v.y, (f16)v.z, (f16)v.w};
    *(double*)(dst + i) = *(double*)hv;
}

// ---------------------------------------------------------------------------
// Mask compaction. Outputs per batch b:
//   cidx[b][i]  : source index of compact position i (pad -> 0)
//   cbias[b][i] : bias (pad -> -1e30)
//   imap[b][t]  : compact position of t, or -1 if masked
//   ccnt[b]     : count padded up to multiple of 64
// ---------------------------------------------------------------------------
__global__ __launch_bounds__(64) void compact_mask(
    const int* __restrict__ mask, const float* __restrict__ abias,
    int* __restrict__ cidx, float* __restrict__ cbias,
    int* __restrict__ imap, int* __restrict__ ccount)
{
    const int b = blockIdx.x;
    const int lane = threadIdx.x;
    int* ip = cidx + b * T_LEN;
    float* bp = cbias + b * T_LEN;
    int* mp = imap + b * T_LEN;

    int base = 0;
    for (int c = 0; c < T_LEN / 64; ++c) {
        const int s = c * 64 + lane;
        const int mv = mask[s * BSZ + b];
        const float bv = abias[s * BSZ + b];
        const unsigned long long bal = __ballot(mv == 0);
        const int pos = __popcll(bal & ((1ull << lane) - 1ull));
        if (mv == 0) { ip[base + pos] = s; bp[base + pos] = bv; mp[s] = base + pos; }
        else mp[s] = -1;
        base += __popcll(bal);
    }
    const int npad = (base + 63) & ~63;
    if (lane < npad - base) { ip[base + lane] = 0; bp[base + lane] = -1e30f; }
    if (lane == 0) ccount[b] = npad;
}

// ---------------------------------------------------------------------------
// fp16 MFMA GEMM, m97 structure: global_load_lds(16B) staging, linear LDS
// [128][32] with source-side XOR swizzle (chunk' = chunk ^ ((row>>1)&3)),
// same XOR on frag reads -> 2-way (free) LDS banking.
// MODE 0: C fp32 MxN.
// MODE 1: q -> qb[bh][t][d] (*0.125); k -> kc[bh][imap(t)][d]; v -> vb[bh][t][d]
// ---------------------------------------------------------------------------
template <int MODE>
__global__ __launch_bounds__(256) void gemm_h(
    const f16* __restrict__ A, const f16* __restrict__ W,
    const float* __restrict__ bias, float* __restrict__ C,
    f16* __restrict__ qb, f16* __restrict__ kc, f16* __restrict__ vb,
    const int* __restrict__ imap, int M, int N, int K)
{
    __shared__ __align__(16) f16 As[128][32];
    __shared__ __align__(16) f16 Bs[128][32];

    const int tid = threadIdx.x;
    const int w = tid >> 6, l = tid & 63;
    const int wr = w >> 1, wc = w & 1;
    const int lg = l >> 4, lr = l & 15;

    const int bm = blockIdx.x * 128, bn = blockIdx.y * 128;

    // staging: chunk c = w*128 + it*64 + l ; row = c>>2 ; swizzled col chunk
    int srow[2], sqc[2];
#pragma unroll
    for (int it = 0; it < 2; ++it) {
        const int c = w * 128 + it * 64 + l;
        srow[it] = c >> 2;
        sqc[it] = (c & 3) ^ ((srow[it] >> 1) & 3);
    }

    f32x4 acc[4][4];
#pragma unroll
    for (int i = 0; i < 4; ++i)
#pragma unroll
        for (int j = 0; j < 4; ++j) acc[i][j] = (f32x4)(0.f);

    const int cq = lg ^ ((lr >> 1) & 3);   // frag-read swizzled chunk

    for (int kt = 0; kt < K; kt += 32) {
        __syncthreads();
#pragma unroll
        for (int it = 0; it < 2; ++it) {
            const int ldsb = (w * 128 + it * 64) * 16;
            gload16(A + (size_t)(bm + srow[it]) * K + kt + sqc[it] * 8,
                    (char*)&As[0][0] + ldsb);
            gload16(W + (size_t)(bn + srow[it]) * K + kt + sqc[it] * 8,
                    (char*)&Bs[0][0] + ldsb);
        }
        __syncthreads();

        f16x8 af[4], bf[4];
#pragma unroll
        for (int am = 0; am < 4; ++am)
            af[am] = *(const f16x8*)((const char*)&As[0][0] +
                     (wr * 64 + am * 16 + lr) * 64 + cq * 16);
#pragma unroll
        for (int bnf = 0; bnf < 4; ++bnf)
            bf[bnf] = *(const f16x8*)((const char*)&Bs[0][0] +
                      (wc * 64 + bnf * 16 + lr) * 64 + cq * 16);
#pragma unroll
        for (int am = 0; am < 4; ++am)
#pragma unroll
            for (int bnf = 0; bnf < 4; ++bnf)
                acc[am][bnf] = MFMA16(af[am], bf[bnf], acc[am][bnf]);
    }

    const int colb = bn + wc * 64;
    const int rowb = bm + wr * 64;
    float bv[4];
#pragma unroll
    for (int j = 0; j < 4; ++j) bv[j] = bias[colb + j * 16 + lr];

    if (MODE == 0) {
#pragma unroll
        for (int am = 0; am < 4; ++am)
#pragma unroll
            for (int bnf = 0; bnf < 4; ++bnf)
#pragma unroll
                for (int rg = 0; rg < 4; ++rg) {
                    const int row = rowb + am * 16 + lg * 4 + rg;
                    const int col = colb + bnf * 16 + lr;
                    C[(size_t)row * N + col] = acc[am][bnf][rg] + bv[bnf];
                }
    } else {
        const int sec = bn / EMB;   // 128-col blocks never straddle a section
        const float scale = (sec == 0) ? 0.125f : 1.0f;
#pragma unroll
        for (int bnf = 0; bnf < 4; ++bnf) {
            const int col = colb + bnf * 16 + lr;
            const int e = col - sec * EMB;
            const int h = e >> 6, d = e & 63;
#pragma unroll
            for (int am = 0; am < 4; ++am)
#pragma unroll
                for (int rg = 0; rg < 4; ++rg) {
                    const int row = rowb + am * 16 + lg * 4 + rg;
                    const int t = row >> 2, b = row & 3;
                    const f16 val = (f16)((acc[am][bnf][rg] + bv[bnf]) * scale);
                    if (sec == 0) {
                        qb[((size_t)((b * NH + h) * T_LEN + t)) * DH + d] = val;
                    } else if (sec == 1) {
                        const int ip = imap[b * T_LEN + t];
                        if (ip >= 0)
                            kc[((size_t)((b * NH + h) * T_LEN + ip)) * DH + d] = val;
                    } else {
                        vb[((size_t)((b * NH + h) * T_LEN + t)) * DH + d] = val;
                    }
                }
        }
    }
}

// ---------------------------------------------------------------------------
// One-time V gather + transpose: vb[bh][t][d] -> vct[bh][d][compact_i]
// via LDS tile transpose. Block = (64 compact rows, bh).
// ---------------------------------------------------------------------------
__global__ __launch_bounds__(256) void gather_vT(
    const f16* __restrict__ vb, const int* __restrict__ cidx,
    const int* __restrict__ ccnt, f16* __restrict__ vct)
{
    __shared__ f16 Vl[64][72];
    const int bh = blockIdx.y, b = bh / NH;
    const int i0 = blockIdx.x * 64;
    if (i0 >= ccnt[b]) return;
    const int tid = threadIdx.x;
    const size_t base = (size_t)bh * T_LEN * DH;

#pragma unroll
    for (int half = 0; half < 2; ++half) {
        const int c = half * 256 + tid;
        const int row = c >> 3, cc = c & 7;
        const int src = cidx[b * T_LEN + i0 + row];
        *(int4*)&Vl[row][cc * 8] =
            *(const int4*)(vb + base + (size_t)src * DH + cc * 8);
    }
    __syncthreads();
    const int dr = tid >> 2, ic = tid & 3;
    f16 tmp[16];
#pragma unroll
    for (int jj = 0; jj < 16; ++jj) tmp[jj] = Vl[ic * 16 + jj][dr];
    f16* dst = vct + ((size_t)bh * DH + dr) * T_LEN + i0 + ic * 16;
    *(int4*)(dst)     = *(int4*)&tmp[0];
    *(int4*)(dst + 8) = *(int4*)&tmp[8];
}

// ---------------------------------------------------------------------------
// MFMA flash attention v2. Block: 1 head x 128 q, 4 waves x 32 q.
// KVBLK=64 over compacted src (no indirection). K tile [64 src][64 d] and
// V^T tile [64 d][64 src] staged via global_load_lds with row&7 XOR swizzle
// (source pre-swizzled, read swizzled). P per-wave LDS [32][72].
// ---------------------------------------------------------------------------
__global__ __launch_bounds__(256) void attn_mfma(
    const f16* __restrict__ qh, const f16* __restrict__ kcb,
    const f16* __restrict__ vct, const float* __restrict__ cbias,
    const int* __restrict__ ccnt, f16* __restrict__ abh)
{
    __shared__ __align__(16) f16 Kt[64][64];
    __shared__ __align__(16) f16 Vt[64][64];     // [dh][src]
    __shared__ __align__(16) f16 Pl[4][32][72];  // rows 144B (16B-aligned)
    __shared__ float bias_l[64];

    const int bh = blockIdx.y, b = bh / NH, h = bh % NH;
    const int tid = threadIdx.x, w = tid >> 6, l = tid & 63;
    const int lg = l >> 4, lr = l & 15;
    const size_t base = (size_t)bh * T_LEN * DH;
    const int q0 = blockIdx.x * 128 + w * 32;

    f16x8 qf[2][2];
#pragma unroll
    for (int mi = 0; mi < 2; ++mi)
#pragma unroll
        for (int ki = 0; ki < 2; ++ki)
            qf[mi][ki] = *(const f16x8*)(qh + base +
                (size_t)(q0 + mi * 16 + lr) * DH + ki * 32 + lg * 8);

    f32x4 o[2][4];
#pragma unroll
    for (int mi = 0; mi < 2; ++mi)
#pragma unroll
        for (int bn = 0; bn < 4; ++bn) o[mi][bn] = (f32x4)(0.f);
    float mrow[2][4], lrow[2][4];
#pragma unroll
    for (int mi = 0; mi < 2; ++mi)
#pragma unroll
        for (int rg = 0; rg < 4; ++rg) { mrow[mi][rg] = -1e30f; lrow[mi][rg] = 0.f; }

    const int npad = ccnt[b];
    const float* biasp = cbias + b * T_LEN;
    const f16* kbase = kcb + base;
    const f16* vtbase = vct + (size_t)bh * DH * T_LEN;

    int srow[2], scc[2];
#pragma unroll
    for (int it = 0; it < 2; ++it) {
        const int c = w * 128 + it * 64 + l;
        srow[it] = c >> 3;
        scc[it] = (c & 7) ^ (srow[it] & 7);
    }

    for (int i0 = 0; i0 < npad; i0 += 64) {
        __syncthreads();
#pragma unroll
        for (int it = 0; it < 2; ++it) {
            const int ldsb = (w * 128 + it * 64) * 16;
            gload16(kbase + (size_t)(i0 + srow[it]) * DH + scc[it] * 8,
                    (char*)&Kt[0][0] + ldsb);
            gload16(vtbase + (size_t)srow[it] * T_LEN + i0 + scc[it] * 8,
                    (char*)&Vt[0][0] + ldsb);
        }
        if (tid < 64) bias_l[tid] = biasp[i0 + tid];
        __syncthreads();

        // --- S = Q K^T ---
        f32x4 s[2][4];
#pragma unroll
        for (int mi = 0; mi < 2; ++mi)
#pragma unroll
            for (int ni = 0; ni < 4; ++ni) s[mi][ni] = (f32x4)(0.f);
#pragma unroll
        for (int ni = 0; ni < 4; ++ni) {
            const int row = ni * 16 + lr;
#pragma unroll
            for (int ki = 0; ki < 2; ++ki) {
                const int cq = (ki * 4 + lg) ^ (row & 7);
                const f16x8 kf = *(const f16x8*)((const char*)&Kt[0][0] +
                                 row * 128 + cq * 16);
#pragma unroll
                for (int mi = 0; mi < 2; ++mi)
                    s[mi][ni] = MFMA16(qf[mi][ki], kf, s[mi][ni]);
            }
        }

        // --- bias + online softmax (row = lg*4+rg, col = lr within ni) ---
        float bcol[4];
#pragma unroll
        for (int ni = 0; ni < 4; ++ni) bcol[ni] = bias_l[ni * 16 + lr];

        float r_[2][4], p[2][4][4];
#pragma unroll
        for (int mi = 0; mi < 2; ++mi)
#pragma unroll
            for (int rg = 0; rg < 4; ++rg) {
                float sv[4];
#pragma unroll
                for (int ni = 0; ni < 4; ++ni) sv[ni] = s[mi][ni][rg] + bcol[ni];
                float mx = fmaxf(fmaxf(sv[0], sv[1]), fmaxf(sv[2], sv[3]));
                mx = fmaxf(mx, __shfl_xor(mx, 1));
                mx = fmaxf(mx, __shfl_xor(mx, 2));
                mx = fmaxf(mx, __shfl_xor(mx, 4));
                mx = fmaxf(mx, __shfl_xor(mx, 8));
                const float newm = fmaxf(mrow[mi][rg], mx);
                r_[mi][rg] = __expf(mrow[mi][rg] - newm);
                mrow[mi][rg] = newm;
                float ps = 0.f;
#pragma unroll
                for (int ni = 0; ni < 4; ++ni) {
                    p[mi][ni][rg] = __expf(sv[ni] - newm);
                    ps += p[mi][ni][rg];
                }
                ps += __shfl_xor(ps, 1);
                ps += __shfl_xor(ps, 2);
                ps += __shfl_xor(ps, 4);
                ps += __shfl_xor(ps, 8);
                lrow[mi][rg] = lrow[mi][rg] * r_[mi][rg] + ps;
            }

        // --- P -> per-wave LDS (C-layout -> A-frag layout) ---
#pragma unroll
        for (int mi = 0; mi < 2; ++mi)
#pragma unroll
            for (int ni = 0; ni < 4; ++ni)
#pragma unroll
                for (int rg = 0; rg < 4; ++rg)
                    Pl[w][mi * 16 + lg * 4 + rg][ni * 16 + lr] = (f16)p[mi][ni][rg];

        // --- rescale O, then O += P V ---
#pragma unroll
        for (int mi = 0; mi < 2; ++mi)
#pragma unroll
            for (int bn = 0; bn < 4; ++bn)
#pragma unroll
                for (int rg = 0; rg < 4; ++rg) o[mi][bn][rg] *= r_[mi][rg];

        f16x8 pf[2][2];
#pragma unroll
        for (int mi = 0; mi < 2; ++mi)
#pragma unroll
            for (int ki = 0; ki < 2; ++ki)
                pf[mi][ki] = *(const f16x8*)((const char*)&Pl[w][0][0] +
                             (mi * 16 + lr) * 144 + ki * 64 + lg * 16);
#pragma unroll
        for (int bn = 0; bn < 4; ++bn) {
            const int row = bn * 16 + lr;
#pragma unroll
            for (int ki = 0; ki < 2; ++ki) {
                const int cq = (ki * 4 + lg) ^ (row & 7);
                const f16x8 vf = *(const f16x8*)((const char*)&Vt[0][0] +
                                 row * 128 + cq * 16);
#pragma unroll
                for (int mi = 0; mi < 2; ++mi)
                    o[mi][bn] = MFMA16(pf[mi][ki], vf, o[mi][bn]);
            }
        }
    }

    // --- epilogue: normalize, write abh [tok][EMB] fp16 ---
#pragma unroll
    for (int mi = 0; mi < 2; ++mi)
#pragma unroll
        for (int rg = 0; rg < 4; ++rg) {
            const float inv = 1.f / lrow[mi][rg];
            const int q = q0 + mi * 16 + lg * 4 + rg;
#pragma unroll
            for (int bn = 0; bn < 4; ++bn) {
                const int col = h * DH + bn * 16 + lr;
                abh[(size_t)(q * BSZ + b) * EMB + col] = (f16)(o[mi][bn][rg] * inv);
            }
        }
}

// ---------------------------------------------------------------------------
extern "C" void kernel_launch(void* const* d_in, const int* in_sizes, int n_in,
                              void* d_out, int out_size, void* d_ws, size_t ws_size,
                              hipStream_t stream)
{
    const float* x     = (const float*)d_in[0];
    const int*   mask  = (const int*)d_in[1];
    const float* abias = (const float*)d_in[2];
    const float* wqkv  = (const float*)d_in[3];
    const float* bqkv  = (const float*)d_in[4];
    const float* wout  = (const float*)d_in[5];
    const float* bout  = (const float*)d_in[6];
    float* out = (float*)d_out;

    const int n_x  = NTOK * EMB;
    const int n_wq = N_QKV * EMB;
    const int n_wo = EMB * EMB;
    const size_t per = (size_t)BH * T_LEN * DH;   // 6,291,456 f16

    f16* xh    = (f16*)d_ws;
    f16* wqkvh = xh + n_x;
    f16* wouth = wqkvh + n_wq;
    f16* qhb   = wouth + n_wo;
    f16* kcb   = qhb + per;    // compacted K
    f16* vhb   = kcb + per;    // V (t-order)
    f16* abh   = vhb + per;
    f16* vct   = abh + per;    // V^T compacted [bh][d][i]
    float* cbias = (float*)(vct + per);
    int*   cidx  = (int*)(cbias + BSZ * T_LEN);
    int*   imap  = cidx + BSZ * T_LEN;
    int*   ccnt  = imap + BSZ * T_LEN;

    compact_mask<<<BSZ, 64, 0, stream>>>(mask, abias, cidx, cbias, imap, ccnt);

    const int tot4 = (n_x + n_wq + n_wo) / 4;
    conv3<<<(tot4 + 255) / 256, 256, 0, stream>>>(
        x, wqkv, wout, n_x, n_wq, n_wo, xh);

    gemm_h<1><<<dim3(NTOK / 128, N_QKV / 128), 256, 0, stream>>>(
        xh, wqkvh, bqkv, nullptr, qhb, kcb, vhb, imap, NTOK, N_QKV, EMB);

    gather_vT<<<dim3(T_LEN / 64, BH), 256, 0, stream>>>(vhb, cidx, ccnt, vct);

    attn_mfma<<<dim3(T_LEN / 128, BH), 256, 0, stream>>>(
        qhb, kcb, vct, cbias, ccnt, abh);

    gemm_h<0><<<dim3(NTOK / 128, EMB / 128), 256, 0, stream>>>(
        abh, wouth, bout, out, nullptr, nullptr, nullptr, nullptr,
        NTOK, EMB, EMB);
}

// Round 6
// 246.074 us; speedup vs baseline: 9.2971x; 1.2284x over previous
//
#include <hip/hip_runtime.h>
#include <math.h>

#define T_LEN 2048
#define BSZ   4
#define EMB   768
#define NH    12
#define DH    64
#define NTOK  (T_LEN * BSZ)      // 8192
#define N_QKV (3 * EMB)          // 2304
#define BH    (BSZ * NH)         // 48
#define CONVB 8448               // (n_x + n_wq + n_wo)/4/256

typedef _Float16 f16;
typedef _Float16 f16x8 __attribute__((ext_vector_type(8)));
typedef _Float16 f16x4 __attribute__((ext_vector_type(4)));
typedef float    f32x4 __attribute__((ext_vector_type(4)));

#define MFMA32(a, b, c) __builtin_amdgcn_mfma_f32_16x16x32_f16(a, b, c, 0, 0, 0)
#define MFMA16(a, b, c) __builtin_amdgcn_mfma_f32_16x16x16f16(a, b, c, 0, 0, 0)

// async global->LDS, 16B per lane; LDS dest = wave-uniform base + lane*16
__device__ __forceinline__ void gload16(const void* g, void* l) {
    __builtin_amdgcn_global_load_lds(
        (const __attribute__((address_space(1))) void*)g,
        (__attribute__((address_space(3))) void*)l, 16, 0, 0);
}

// ---------------------------------------------------------------------------
// Fused: fp32->fp16 conversion (blocks 0..CONVB-1) + mask compaction
// (blocks CONVB..CONVB+BSZ-1, one block of 256 per batch).
// compact outputs per batch b:
//   cidx[b][i]: src index of compact pos i (pad->0); cbias: bias (pad->-1e30)
//   imap[b][t]: compact pos of t or -1; ccnt[b]: count padded to mult of 64
// ---------------------------------------------------------------------------
__global__ __launch_bounds__(256) void conv_compact(
    const float* __restrict__ s0, const float* __restrict__ s1,
    const float* __restrict__ s2, f16* __restrict__ dst,
    const int* __restrict__ mask, const float* __restrict__ abias,
    int* __restrict__ cidx, float* __restrict__ cbias,
    int* __restrict__ imap, int* __restrict__ ccount)
{
    const int tid = threadIdx.x;
    if (blockIdx.x < CONVB) {
        const int n0 = NTOK * EMB, n1 = N_QKV * EMB, n2 = EMB * EMB;
        const int i = (blockIdx.x * 256 + tid) * 4;
        const int t01 = n0 + n1;
        const float* s;
        int off;
        if (i < n0)            { s = s0; off = i; }
        else if (i < t01)      { s = s1; off = i - n0; }
        else if (i < t01 + n2) { s = s2; off = i - t01; }
        else return;
        const float4 v = *(const float4*)(s + off);
        f16 hv[4] = {(f16)v.x, (f16)v.y, (f16)v.z, (f16)v.w};
        *(double*)(dst + i) = *(double*)hv;
        return;
    }

    // ---- compaction ----
    const int b = blockIdx.x - CONVB;
    __shared__ int cnt[32], off_l[32], tot[2];
    const int wv = tid >> 6, lane = tid & 63;
    int* ip = cidx + b * T_LEN;
    float* bp = cbias + b * T_LEN;
    int* mp = imap + b * T_LEN;

    for (int i = 0; i < 8; ++i) {
        const int c = wv * 8 + i;
        const int s = c * 64 + lane;
        const int mv = mask[s * BSZ + b];
        const unsigned long long bal = __ballot(mv == 0);
        if (lane == 0) cnt[c] = __popcll(bal);
    }
    __syncthreads();
    if (tid == 0) {
        int acc = 0;
        for (int c = 0; c < 32; ++c) { off_l[c] = acc; acc += cnt[c]; }
        const int npad = (acc + 63) & ~63;
        tot[0] = acc; tot[1] = npad;
        ccount[b] = npad;
    }
    __syncthreads();
    for (int i = 0; i < 8; ++i) {
        const int c = wv * 8 + i;
        const int s = c * 64 + lane;
        const int mv = mask[s * BSZ + b];
        const float bv = abias[s * BSZ + b];
        const unsigned long long bal = __ballot(mv == 0);
        const int pos = __popcll(bal & ((1ull << lane) - 1ull));
        const int basec = off_l[c];
        if (mv == 0) { ip[basec + pos] = s; bp[basec + pos] = bv; mp[s] = basec + pos; }
        else mp[s] = -1;
    }
    const int baseT = tot[0], npad = tot[1];
    if (tid < npad - baseT) { ip[baseT + tid] = 0; bp[baseT + tid] = -1e30f; }
}

// ---------------------------------------------------------------------------
// fp16 MFMA GEMM (m97 structure): global_load_lds(16B), linear LDS [128][32]
// with source-side XOR swizzle, same XOR on frag reads.
// MODE 0: C fp32 MxN.
// MODE 1: q->qb[bh][t][d]*0.125; k->kc[bh][imap(t)][d]; v->vb[bh][t][d]
// ---------------------------------------------------------------------------
template <int MODE>
__global__ __launch_bounds__(256) void gemm_h(
    const f16* __restrict__ A, const f16* __restrict__ W,
    const float* __restrict__ bias, float* __restrict__ C,
    f16* __restrict__ qb, f16* __restrict__ kc, f16* __restrict__ vb,
    const int* __restrict__ imap, int M, int N, int K)
{
    __shared__ __align__(16) f16 As[128][32];
    __shared__ __align__(16) f16 Bs[128][32];

    const int tid = threadIdx.x;
    const int w = tid >> 6, l = tid & 63;
    const int wr = w >> 1, wc = w & 1;
    const int lg = l >> 4, lr = l & 15;

    const int bm = blockIdx.x * 128, bn = blockIdx.y * 128;

    int srow[2], sqc[2];
#pragma unroll
    for (int it = 0; it < 2; ++it) {
        const int c = w * 128 + it * 64 + l;
        srow[it] = c >> 2;
        sqc[it] = (c & 3) ^ ((srow[it] >> 1) & 3);
    }

    f32x4 acc[4][4];
#pragma unroll
    for (int i = 0; i < 4; ++i)
#pragma unroll
        for (int j = 0; j < 4; ++j) acc[i][j] = (f32x4)(0.f);

    const int cq = lg ^ ((lr >> 1) & 3);

    for (int kt = 0; kt < K; kt += 32) {
        __syncthreads();
#pragma unroll
        for (int it = 0; it < 2; ++it) {
            const int ldsb = (w * 128 + it * 64) * 16;
            gload16(A + (size_t)(bm + srow[it]) * K + kt + sqc[it] * 8,
                    (char*)&As[0][0] + ldsb);
            gload16(W + (size_t)(bn + srow[it]) * K + kt + sqc[it] * 8,
                    (char*)&Bs[0][0] + ldsb);
        }
        __syncthreads();

        f16x8 af[4], bf[4];
#pragma unroll
        for (int am = 0; am < 4; ++am)
            af[am] = *(const f16x8*)((const char*)&As[0][0] +
                     (wr * 64 + am * 16 + lr) * 64 + cq * 16);
#pragma unroll
        for (int bnf = 0; bnf < 4; ++bnf)
            bf[bnf] = *(const f16x8*)((const char*)&Bs[0][0] +
                      (wc * 64 + bnf * 16 + lr) * 64 + cq * 16);
#pragma unroll
        for (int am = 0; am < 4; ++am)
#pragma unroll
            for (int bnf = 0; bnf < 4; ++bnf)
                acc[am][bnf] = MFMA32(af[am], bf[bnf], acc[am][bnf]);
    }

    const int colb = bn + wc * 64;
    const int rowb = bm + wr * 64;
    float bv[4];
#pragma unroll
    for (int j = 0; j < 4; ++j) bv[j] = bias[colb + j * 16 + lr];

    if (MODE == 0) {
#pragma unroll
        for (int am = 0; am < 4; ++am)
#pragma unroll
            for (int bnf = 0; bnf < 4; ++bnf)
#pragma unroll
                for (int rg = 0; rg < 4; ++rg) {
                    const int row = rowb + am * 16 + lg * 4 + rg;
                    const int col = colb + bnf * 16 + lr;
                    C[(size_t)row * N + col] = acc[am][bnf][rg] + bv[bnf];
                }
    } else {
        const int sec = bn / EMB;
        const float scale = (sec == 0) ? 0.125f : 1.0f;
#pragma unroll
        for (int bnf = 0; bnf < 4; ++bnf) {
            const int col = colb + bnf * 16 + lr;
            const int e = col - sec * EMB;
            const int h = e >> 6, d = e & 63;
#pragma unroll
            for (int am = 0; am < 4; ++am)
#pragma unroll
                for (int rg = 0; rg < 4; ++rg) {
                    const int row = rowb + am * 16 + lg * 4 + rg;
                    const int t = row >> 2, bb = row & 3;
                    const f16 val = (f16)((acc[am][bnf][rg] + bv[bnf]) * scale);
                    if (sec == 0) {
                        qb[((size_t)((bb * NH + h) * T_LEN + t)) * DH + d] = val;
                    } else if (sec == 1) {
                        const int ipv = imap[bb * T_LEN + t];
                        if (ipv >= 0)
                            kc[((size_t)((bb * NH + h) * T_LEN + ipv)) * DH + d] = val;
                    } else {
                        vb[((size_t)((bb * NH + h) * T_LEN + t)) * DH + d] = val;
                    }
                }
        }
    }
}

// ---------------------------------------------------------------------------
// One-time V gather + transpose: vb[bh][t][d] -> vct[bh][d][compact_i]
// ---------------------------------------------------------------------------
__global__ __launch_bounds__(256) void gather_vT(
    const f16* __restrict__ vb, const int* __restrict__ cidx,
    const int* __restrict__ ccnt, f16* __restrict__ vct)
{
    __shared__ f16 Vl[64][72];
    const int bh = blockIdx.y, b = bh / NH;
    const int i0 = blockIdx.x * 64;
    if (i0 >= ccnt[b]) return;
    const int tid = threadIdx.x;
    const size_t base = (size_t)bh * T_LEN * DH;

#pragma unroll
    for (int half = 0; half < 2; ++half) {
        const int c = half * 256 + tid;
        const int row = c >> 3, cc = c & 7;
        const int src = cidx[b * T_LEN + i0 + row];
        *(int4*)&Vl[row][cc * 8] =
            *(const int4*)(vb + base + (size_t)src * DH + cc * 8);
    }
    __syncthreads();
    const int dr = tid >> 2, ic = tid & 3;
    f16 tmp[16];
#pragma unroll
    for (int jj = 0; jj < 16; ++jj) tmp[jj] = Vl[ic * 16 + jj][dr];
    f16* dst = vct + ((size_t)bh * DH + dr) * T_LEN + i0 + ic * 16;
    *(int4*)(dst)     = *(int4*)&tmp[0];
    *(int4*)(dst + 8) = *(int4*)&tmp[8];
}

// ---------------------------------------------------------------------------
// MFMA flash attention v3: swapped-operand S^T = mfma(K, Q) so softmax is
// lane-local (col = q = lane&15); P stays in registers and feeds PV directly
// as the B-operand of mfma_f32_16x16x16f16 (k-map == lane-local s values).
// O^T = mfma(V^T, P). Single-barrier double-buffered K/V staging.
// ---------------------------------------------------------------------------
__global__ __launch_bounds__(256) void attn_mfma(
    const f16* __restrict__ qh, const f16* __restrict__ kcb,
    const f16* __restrict__ vct, const float* __restrict__ cbias,
    const int* __restrict__ ccnt, f16* __restrict__ abh)
{
    __shared__ __align__(16) f16 Kt[2][64][64];   // [buf][src][d]
    __shared__ __align__(16) f16 Vt[2][64][64];   // [buf][d][src]
    __shared__ float bias_l[2][64];

    const int bh = blockIdx.y, b = bh / NH, h = bh % NH;
    const int tid = threadIdx.x, w = tid >> 6, l = tid & 63;
    const int lg = l >> 4, lr = l & 15;
    const size_t base = (size_t)bh * T_LEN * DH;
    const int q0 = blockIdx.x * 128 + w * 32;

    // Q fragments (used as B operand; same lane->row/k map as A)
    f16x8 qf[2][2];
#pragma unroll
    for (int mi = 0; mi < 2; ++mi)
#pragma unroll
        for (int ki = 0; ki < 2; ++ki)
            qf[mi][ki] = *(const f16x8*)(qh + base +
                (size_t)(q0 + mi * 16 + lr) * DH + ki * 32 + lg * 8);

    f32x4 o[4][2];   // O^T tiles: [d-tile][q-tile]
#pragma unroll
    for (int dt = 0; dt < 4; ++dt)
#pragma unroll
        for (int mi = 0; mi < 2; ++mi) o[dt][mi] = (f32x4)(0.f);
    float m_[2] = {-1e30f, -1e30f}, l_[2] = {0.f, 0.f};

    const int npad = ccnt[b];
    const float* biasp = cbias + b * T_LEN;
    const f16* kbase = kcb + base;
    const f16* vtbase = vct + (size_t)bh * DH * T_LEN;

    int srow[2], scc[2];
#pragma unroll
    for (int it = 0; it < 2; ++it) {
        const int c = w * 128 + it * 64 + l;
        srow[it] = c >> 3;
        scc[it] = (c & 7) ^ (srow[it] & 7);
    }

    auto stage = [&](int buf, int i0s) {
#pragma unroll
        for (int it = 0; it < 2; ++it) {
            const int ldsb = (w * 128 + it * 64) * 16;
            gload16(kbase + (size_t)(i0s + srow[it]) * DH + scc[it] * 8,
                    (char*)&Kt[buf][0][0] + ldsb);
            gload16(vtbase + (size_t)srow[it] * T_LEN + i0s + scc[it] * 8,
                    (char*)&Vt[buf][0][0] + ldsb);
        }
        if (tid < 64) bias_l[buf][tid] = biasp[i0s + tid];
    };

    stage(0, 0);
    __syncthreads();

    int cur = 0;
    for (int i0 = 0; i0 < npad; i0 += 64, cur ^= 1) {
        if (i0 + 64 < npad) stage(cur ^ 1, i0 + 64);

        // --- S^T = K Q^T : C rows = src, cols = q ---
        f32x4 s[4][2];
#pragma unroll
        for (int ni = 0; ni < 4; ++ni)
#pragma unroll
            for (int mi = 0; mi < 2; ++mi) s[ni][mi] = (f32x4)(0.f);
#pragma unroll
        for (int ni = 0; ni < 4; ++ni) {
            const int row = ni * 16 + lr;
#pragma unroll
            for (int ki = 0; ki < 2; ++ki) {
                const int cq = (ki * 4 + lg) ^ (row & 7);
                const f16x8 kf = *(const f16x8*)((const char*)&Kt[cur][0][0] +
                                 row * 128 + cq * 16);
#pragma unroll
                for (int mi = 0; mi < 2; ++mi)
                    s[ni][mi] = MFMA32(kf, qf[mi][ki], s[ni][mi]);
            }
        }

        // --- bias per lane (src = ni*16 + lg*4 + rg) ---
        float bv[4][4];
#pragma unroll
        for (int ni = 0; ni < 4; ++ni) {
            const float4 b4 = *(const float4*)&bias_l[cur][ni * 16 + lg * 4];
            bv[ni][0] = b4.x; bv[ni][1] = b4.y; bv[ni][2] = b4.z; bv[ni][3] = b4.w;
        }

        // --- softmax per q-col tile mi (16 lane-local vals + 2 shfl) ---
        f16x4 pk[2][4];
        float r_[2];
#pragma unroll
        for (int mi = 0; mi < 2; ++mi) {
            float sv[4][4];
            float mx = -1e30f;
#pragma unroll
            for (int ni = 0; ni < 4; ++ni)
#pragma unroll
                for (int rg = 0; rg < 4; ++rg) {
                    sv[ni][rg] = s[ni][mi][rg] + bv[ni][rg];
                    mx = fmaxf(mx, sv[ni][rg]);
                }
            mx = fmaxf(mx, __shfl_xor(mx, 16));
            mx = fmaxf(mx, __shfl_xor(mx, 32));
            const float newm = fmaxf(m_[mi], mx);
            r_[mi] = __expf(m_[mi] - newm);
            m_[mi] = newm;
            float ps = 0.f;
#pragma unroll
            for (int ni = 0; ni < 4; ++ni) {
                float p0 = __expf(sv[ni][0] - newm);
                float p1 = __expf(sv[ni][1] - newm);
                float p2 = __expf(sv[ni][2] - newm);
                float p3 = __expf(sv[ni][3] - newm);
                ps += (p0 + p1) + (p2 + p3);
                pk[mi][ni] = (f16x4){(f16)p0, (f16)p1, (f16)p2, (f16)p3};
            }
            ps += __shfl_xor(ps, 16);
            ps += __shfl_xor(ps, 32);
            l_[mi] = l_[mi] * r_[mi] + ps;
        }

        // --- rescale O^T ---
#pragma unroll
        for (int dt = 0; dt < 4; ++dt)
#pragma unroll
            for (int mi = 0; mi < 2; ++mi)
#pragma unroll
                for (int rg = 0; rg < 4; ++rg) o[dt][mi][rg] *= r_[mi];

        // --- O^T += V^T P  (16x16x16, k-step ni over src) ---
#pragma unroll
        for (int dt = 0; dt < 4; ++dt) {
            const int row = dt * 16 + lr;
#pragma unroll
            for (int ni = 0; ni < 4; ++ni) {
                const int swc = (ni * 2 + (lg >> 1)) ^ (row & 7);
                const f16x4 vf = *(const f16x4*)((const char*)&Vt[cur][0][0] +
                                 row * 128 + swc * 16 + (lg & 1) * 8);
#pragma unroll
                for (int mi = 0; mi < 2; ++mi)
                    o[dt][mi] = MFMA16(vf, pk[mi][ni], o[dt][mi]);
            }
        }
        __syncthreads();
    }

    // --- epilogue: O^T lane holds (d = dt*16+lg*4+rg, q = mi*16+lr) ---
#pragma unroll
    for (int mi = 0; mi < 2; ++mi) {
        const float inv = 1.f / l_[mi];
        const int q = q0 + mi * 16 + lr;
#pragma unroll
        for (int dt = 0; dt < 4; ++dt) {
            const int d0 = dt * 16 + lg * 4;
            f16x4 ov = {(f16)(o[dt][mi][0] * inv), (f16)(o[dt][mi][1] * inv),
                        (f16)(o[dt][mi][2] * inv), (f16)(o[dt][mi][3] * inv)};
            *(f16x4*)(abh + (size_t)(q * BSZ + b) * EMB + h * DH + d0) = ov;
        }
    }
}

// ---------------------------------------------------------------------------
extern "C" void kernel_launch(void* const* d_in, const int* in_sizes, int n_in,
                              void* d_out, int out_size, void* d_ws, size_t ws_size,
                              hipStream_t stream)
{
    const float* x     = (const float*)d_in[0];
    const int*   mask  = (const int*)d_in[1];
    const float* abias = (const float*)d_in[2];
    const float* wqkv  = (const float*)d_in[3];
    const float* bqkv  = (const float*)d_in[4];
    const float* wout  = (const float*)d_in[5];
    const float* bout  = (const float*)d_in[6];
    float* out = (float*)d_out;

    const int n_x  = NTOK * EMB;
    const int n_wq = N_QKV * EMB;
    const int n_wo = EMB * EMB;
    const size_t per = (size_t)BH * T_LEN * DH;   // 6,291,456 f16

    f16* xh    = (f16*)d_ws;
    f16* wqkvh = xh + n_x;
    f16* wouth = wqkvh + n_wq;
    f16* qhb   = wouth + n_wo;
    f16* kcb   = qhb + per;    // compacted K
    f16* vhb   = kcb + per;    // V (t-order)
    f16* abh   = vhb + per;
    f16* vct   = abh + per;    // V^T compacted [bh][d][i]
    float* cbias = (float*)(vct + per);
    int*   cidx  = (int*)(cbias + BSZ * T_LEN);
    int*   imap  = cidx + BSZ * T_LEN;
    int*   ccnt  = imap + BSZ * T_LEN;

    conv_compact<<<CONVB + BSZ, 256, 0, stream>>>(
        x, wqkv, wout, xh, mask, abias, cidx, cbias, imap, ccnt);

    gemm_h<1><<<dim3(NTOK / 128, N_QKV / 128), 256, 0, stream>>>(
        xh, wqkvh, bqkv, nullptr, qhb, kcb, vhb, imap, NTOK, N_QKV, EMB);

    gather_vT<<<dim3(T_LEN / 64, BH), 256, 0, stream>>>(vhb, cidx, ccnt, vct);

    attn_mfma<<<dim3(T_LEN / 128, BH), 256, 0, stream>>>(
        qhb, kcb, vct, cbias, ccnt, abh);

    gemm_h<0><<<dim3(NTOK / 128, EMB / 128), 256, 0, stream>>>(
        abh, wouth, bout, out, nullptr, nullptr, nullptr, nullptr,
        NTOK, EMB, EMB);
}